// Round 7
// baseline (52.990 us; speedup 1.0000x reference)
//
#include <hip/hip_runtime.h>
#include <hip/hip_bf16.h>
#include <math.h>

// B=2048, N=16384, D=16
#define BB 2048
#define NN 16384
#define KAUG 32                 // augmented K (18 used, padded to MFMA K=32)
#define RSA 40                  // A LDS row stride in ushorts (80 B)
#define RSX 32                  // X LDS row stride in ushorts (64 B)
#define NSLICES 128             // 128 slices x 128 n
#define CHUNKS 8                // 8 x 16-n chunks per slice
#define BT 2                    // b-tiles per wave (32 samples)
#define RF 4                    // PROBE: grid replication factor (identical
                                // redundant blocks -> kde_main visible in prof)
#define LN2 0.6931471805599453f
#define LOG2E 1.4426950408889634f
#define LN2PI 1.8378770664093453f

typedef __attribute__((ext_vector_type(8))) short bf16x8;
typedef __attribute__((ext_vector_type(4))) float f32x4;

__device__ __forceinline__ float EXP2(float v) { return __builtin_amdgcn_exp2f(v); }

// pack two f32 -> one u32 of 2x bf16 (RNE) via v_cvt_pk_bf16_f32
__device__ __forceinline__ unsigned pack_bf2(float a, float b) {
    __hip_bfloat162 h = __float22bfloat162_rn(make_float2(a, b));
    union { __hip_bfloat162 h2; unsigned u; } cvt;
    cvt.h2 = h;
    return cvt.u;
}
__device__ __forceinline__ float lo16f(unsigned u) { return __uint_as_float(u << 16); }
__device__ __forceinline__ float hi16f(unsigned u) { return __uint_as_float(u & 0xFFFF0000u); }

// ---------------------------------------------------------------------------
// K1: fused prep + two-pass MFMA LSE -> partials. RF redundant copies of each
// (slice,bgrp) block write byte-identical partials (deterministic).
// ---------------------------------------------------------------------------
__global__ __launch_bounds__(256, 4) void kde_main(
    const float* __restrict__ x, const float* __restrict__ mu,
    const float* __restrict__ sigt, const float* __restrict__ wt,
    float2* __restrict__ part)
{
    __shared__ ushort AhL[128 * RSA], AlL[128 * RSA];   // 10 KB + 10 KB
    __shared__ ushort XhL[128 * RSX], XlL[128 * RSX];   //  8 KB +  8 KB

    const int tid   = threadIdx.x;
    const int slice = (blockIdx.x >> 4) & (NSLICES - 1);
    const int bgrp  = blockIdx.x & 15;

    // ---------------- phase 1: prep one augmented row per thread ----------
    {
        float v[KAUG];
        #pragma unroll
        for (int k = 18; k < KAUG; ++k) v[k] = 0.f;
        ushort *dh, *dl;
        if (tid < 128) {
            int n = slice * 128 + tid;
            const float4* m4 = (const float4*)(mu + (size_t)n * 16);
            float4 a = m4[0], b = m4[1], c = m4[2], d = m4[3];
            float r[16];
            *(float4*)(r + 0) = a; *(float4*)(r + 4) = b;
            *(float4*)(r + 8) = c; *(float4*)(r + 12) = d;
            float musq = 0.f;
            #pragma unroll
            for (int k = 0; k < 16; ++k) musq = fmaf(r[k], r[k], musq);
            float stv = sigt[n], wv = wt[n];
            float A2 = -0.5f * LOG2E * EXP2(-2.0f * LOG2E * stv);
            float C2 = -LOG2E * (16.f * stv + 8.f * LN2PI) + __log2f(wv);
            #pragma unroll
            for (int k = 0; k < 16; ++k) v[k] = A2 * (-2.f * r[k]);
            v[16] = fmaf(A2, musq, C2);
            v[17] = A2;
            dh = AhL + tid * RSA;
            dl = AlL + tid * RSA;
        } else {
            int b = bgrp * 128 + (tid - 128);
            const float4* x4 = (const float4*)(x + (size_t)b * 16);
            float4 a = x4[0], bb = x4[1], c = x4[2], d = x4[3];
            float r[16];
            *(float4*)(r + 0) = a;  *(float4*)(r + 4) = bb;
            *(float4*)(r + 8) = c;  *(float4*)(r + 12) = d;
            float xsq = 0.f;
            #pragma unroll
            for (int k = 0; k < 16; ++k) { v[k] = r[k]; xsq = fmaf(r[k], r[k], xsq); }
            v[16] = 1.0f;
            v[17] = xsq;
            dh = XhL + (tid - 128) * RSX;
            dl = XlL + (tid - 128) * RSX;
        }
        unsigned uh[16], ul[16];
        #pragma unroll
        for (int k = 0; k < 16; ++k) {
            unsigned h = pack_bf2(v[2*k], v[2*k+1]);
            unsigned l = pack_bf2(v[2*k]   - lo16f(h),
                                  v[2*k+1] - hi16f(h));
            uh[k] = h;  ul[k] = l;
        }
        uint4* ph = (uint4*)dh;
        uint4* pl = (uint4*)dl;
        #pragma unroll
        for (int k = 0; k < 4; ++k) {
            ph[k] = make_uint4(uh[4*k], uh[4*k+1], uh[4*k+2], uh[4*k+3]);
            pl[k] = make_uint4(ul[4*k], ul[4*k+1], ul[4*k+2], ul[4*k+3]);
        }
    }
    __syncthreads();

    // ---------------- phase 2: two-pass MFMA LSE ---------------------------
    const int lane = tid & 63;
    const int wv   = tid >> 6;
    const int l15  = lane & 15, g = lane >> 4;

    bf16x8 bh[BT], bl[BT];
    #pragma unroll
    for (int bt = 0; bt < BT; ++bt) {
        int xr = wv * 32 + bt * 16 + l15;
        bh[bt] = *(const bf16x8*)(XhL + xr * RSX + g * 8);
        bl[bt] = *(const bf16x8*)(XlL + xr * RSX + g * 8);
    }

    // pass 1: per-lane max (no exp2, no serial s-chain)
    float M0 = -INFINITY, M1 = -INFINITY;
    #pragma unroll 2
    for (int c = 0; c < CHUNKS; ++c) {
        int ar = c * 16 + l15;
        bf16x8 ah = *(const bf16x8*)(AhL + ar * RSA + g * 8);
        bf16x8 al = *(const bf16x8*)(AlL + ar * RSA + g * 8);
        {
            f32x4 acc = {0.f, 0.f, 0.f, 0.f};
            acc = __builtin_amdgcn_mfma_f32_16x16x32_bf16(al, bh[0], acc, 0, 0, 0);
            acc = __builtin_amdgcn_mfma_f32_16x16x32_bf16(ah, bl[0], acc, 0, 0, 0);
            acc = __builtin_amdgcn_mfma_f32_16x16x32_bf16(ah, bh[0], acc, 0, 0, 0);
            M0 = fmaxf(M0, fmaxf(fmaxf(acc[0], acc[1]), fmaxf(acc[2], acc[3])));
        }
        {
            f32x4 acc = {0.f, 0.f, 0.f, 0.f};
            acc = __builtin_amdgcn_mfma_f32_16x16x32_bf16(al, bh[1], acc, 0, 0, 0);
            acc = __builtin_amdgcn_mfma_f32_16x16x32_bf16(ah, bl[1], acc, 0, 0, 0);
            acc = __builtin_amdgcn_mfma_f32_16x16x32_bf16(ah, bh[1], acc, 0, 0, 0);
            M1 = fmaxf(M1, fmaxf(fmaxf(acc[0], acc[1]), fmaxf(acc[2], acc[3])));
        }
    }
    M0 = fmaxf(M0, __shfl_xor(M0, 16, 64));
    M0 = fmaxf(M0, __shfl_xor(M0, 32, 64));
    M1 = fmaxf(M1, __shfl_xor(M1, 16, 64));
    M1 = fmaxf(M1, __shfl_xor(M1, 32, 64));

    asm volatile("" ::: "memory");   // forbid cross-pass MFMA CSE

    // pass 2: sum exp2(acc - M); only chain is an add per chunk
    float S0 = 0.f, S1 = 0.f;
    #pragma unroll 2
    for (int c = 0; c < CHUNKS; ++c) {
        int ar = c * 16 + l15;
        bf16x8 ah = *(const bf16x8*)(AhL + ar * RSA + g * 8);
        bf16x8 al = *(const bf16x8*)(AlL + ar * RSA + g * 8);
        {
            f32x4 acc = {0.f, 0.f, 0.f, 0.f};
            acc = __builtin_amdgcn_mfma_f32_16x16x32_bf16(al, bh[0], acc, 0, 0, 0);
            acc = __builtin_amdgcn_mfma_f32_16x16x32_bf16(ah, bl[0], acc, 0, 0, 0);
            acc = __builtin_amdgcn_mfma_f32_16x16x32_bf16(ah, bh[0], acc, 0, 0, 0);
            S0 += (EXP2(acc[0] - M0) + EXP2(acc[1] - M0))
                + (EXP2(acc[2] - M0) + EXP2(acc[3] - M0));
        }
        {
            f32x4 acc = {0.f, 0.f, 0.f, 0.f};
            acc = __builtin_amdgcn_mfma_f32_16x16x32_bf16(al, bh[1], acc, 0, 0, 0);
            acc = __builtin_amdgcn_mfma_f32_16x16x32_bf16(ah, bl[1], acc, 0, 0, 0);
            acc = __builtin_amdgcn_mfma_f32_16x16x32_bf16(ah, bh[1], acc, 0, 0, 0);
            S1 += (EXP2(acc[0] - M1) + EXP2(acc[1] - M1))
                + (EXP2(acc[2] - M1) + EXP2(acc[3] - M1));
        }
    }
    S0 += __shfl_xor(S0, 16, 64);
    S0 += __shfl_xor(S0, 32, 64);
    S1 += __shfl_xor(S1, 16, 64);
    S1 += __shfl_xor(S1, 32, 64);

    if (lane < 16) {
        int b0 = bgrp * 128 + wv * 32 + lane;
        part[(size_t)slice * BB + b0]      = make_float2(M0, S0);
        part[(size_t)slice * BB + b0 + 16] = make_float2(M1, S1);
    }
}

// ---------------------------------------------------------------------------
// K2: reduce, latency-parallel. 32 blocks x 256 thr; 4 threads per sample,
// each merges 32 slices via 4 interleaved chains of depth 8; LDS merge of 4.
// ---------------------------------------------------------------------------
__global__ __launch_bounds__(256) void kde_reduce(
    const float2* __restrict__ part, float* __restrict__ out)
{
    __shared__ float2 sm[4][64];
    const int t  = threadIdx.x;
    const int bl = t & 63, j = t >> 6;
    const int b  = blockIdx.x * 64 + bl;

    float mm[4], ss[4];
    #pragma unroll
    for (int c = 0; c < 4; ++c) { mm[c] = -INFINITY; ss[c] = 0.f; }
    #pragma unroll
    for (int k = 0; k < 8; ++k) {
        #pragma unroll
        for (int c = 0; c < 4; ++c) {
            int sl = j * 32 + c * 8 + k;
            float2 vv = part[(size_t)sl * BB + b];
            float mn = fmaxf(mm[c], vv.x);
            ss[c] = fmaf(ss[c], EXP2(mm[c] - mn), vv.y * EXP2(vv.x - mn));
            mm[c] = mn;
        }
    }
    float mA = fmaxf(fmaxf(mm[0], mm[1]), fmaxf(mm[2], mm[3]));
    float sA = ss[0] * EXP2(mm[0] - mA) + ss[1] * EXP2(mm[1] - mA)
             + ss[2] * EXP2(mm[2] - mA) + ss[3] * EXP2(mm[3] - mA);
    sm[j][bl] = make_float2(mA, sA);
    __syncthreads();
    if (j == 0) {
        float2 v0 = sm[0][bl], v1 = sm[1][bl], v2 = sm[2][bl], v3 = sm[3][bl];
        float M = fmaxf(fmaxf(v0.x, v1.x), fmaxf(v2.x, v3.x));
        float S = v0.y * EXP2(v0.x - M) + v1.y * EXP2(v1.x - M)
                + v2.y * EXP2(v2.x - M) + v3.y * EXP2(v3.x - M);
        out[b] = (M + __log2f(S)) * LN2;
    }
}

extern "C" void kernel_launch(void* const* d_in, const int* in_sizes, int n_in,
                              void* d_out, int out_size, void* d_ws, size_t ws_size,
                              hipStream_t stream) {
    const float* x  = (const float*)d_in[0];
    const float* mu = (const float*)d_in[1];
    const float* st = (const float*)d_in[2];
    const float* w  = (const float*)d_in[3];
    float* out = (float*)d_out;

    float2* part = (float2*)d_ws;                          // 128*2048*8 = 2 MB

    hipLaunchKernelGGL(kde_main, dim3(NSLICES * 16 * RF), dim3(256), 0, stream,
                       x, mu, st, w, part);
    hipLaunchKernelGGL(kde_reduce, dim3(BB / 64), dim3(256), 0, stream,
                       part, out);
}